// Round 6
// baseline (353.712 us; speedup 1.0000x reference)
//
#include <hip/hip_runtime.h>

#define D        128
#define N_GRAPHS 64
#define N_CLS    16
#define LDA      40   // mm1m LDS row stride in bf16 (80 B: 16B-aligned, 2-way banks = free)
#define SLOTS    48   // padded CSR width; deg ~ Poisson(16), P(>48) ~ 1e-11
#define CAP      8192 // bucket capacity (avg 4096, std ~64 -> 2x margin)

typedef unsigned int   uint;
typedef unsigned short ushort;
typedef __attribute__((ext_vector_type(8))) short short8;
typedef __attribute__((ext_vector_type(4))) float f32x4;

__device__ inline ushort f2b(float f) {   // f32 -> bf16 RNE
    uint u = __float_as_uint(f);
    u += 0x7fffu + ((u >> 16) & 1u);
    return (ushort)(u >> 16);
}

// swizzled u16 index into a [row][256] LDS tile.
// XOR by ((row ^ (row>>3)) & 7) << 3: keeps 8-u16 (16 B) groups intact for
// b128 reads; varies with BOTH row&7 (spreads MFMA-read lanes) and row>>3
// (spreads transpose-staging writes). Both patterns <=2-way.
__device__ __forceinline__ int swz2i(int row, int col) {
    return row * 256 + (col ^ (((row ^ (row >> 3)) & 7) << 3));
}

// ===================== dispatch 1: boot (part | castw | gbound | cast) ======

__global__ __launch_bounds__(256) void k_boot(
    const float* __restrict__ h, ushort* __restrict__ fb,
    const float* __restrict__ Ws, const float* __restrict__ Wn,
    ushort* __restrict__ wT,
    const int* __restrict__ gid, int* __restrict__ gstart,
    const int* __restrict__ src, const int* __restrict__ dst,
    int* __restrict__ bcount, uint* __restrict__ ebuf,
    int E, int NB, int N, int t4) {
    __shared__ int hist[512], base[512], lcur[512];
    int bb = blockIdx.x;
    int t  = threadIdx.x;

    if (bb < 256) {
        // ---- partition edges into 256-node buckets by dst ----
        int per = (E + 255) / 256;
        int e0 = bb * per;
        int e1 = min(e0 + per, E);
        for (int i = t; i < NB; i += 256) { hist[i] = 0; lcur[i] = 0; }
        __syncthreads();
        for (int e = e0 + t; e < e1; e += 256) atomicAdd(&hist[dst[e] >> 8], 1);
        __syncthreads();
        for (int i = t; i < NB; i += 256)
            base[i] = hist[i] ? atomicAdd(&bcount[i], hist[i]) : 0;
        __syncthreads();
        for (int e = e0 + t; e < e1; e += 256) {
            int dd = dst[e];
            int b = dd >> 8;
            int off = atomicAdd(&lcur[b], 1);
            int pos = base[b] + off;
            if (pos < CAP)
                ebuf[(size_t)b * CAP + pos] = ((uint)src[e] << 8) | (uint)(dd & 255);
        }
    } else if (bb < 384) {
        // ---- castw: wT[col][k] (k=0..255: Ws rows then Wn rows), bf16 ----
        int i = (bb - 256) * 256 + t;   // 0..32767
        int c = i >> 8, k = i & 255;
        float v = (k < 128) ? Ws[k * 128 + c] : Wn[(k - 128) * 128 + c];
        wT[c * 256 + k] = f2b(v);
    } else if (bb == 384) {
        // ---- gbound: gstart[g] = lower_bound(gid, g) ----
        int g = t;
        if (g <= N_GRAPHS) {
            int lo = 0, hi = N;
            while (lo < hi) {
                int mid = (lo + hi) >> 1;
                if (gid[mid] < g) lo = mid + 1; else hi = mid;
            }
            gstart[g] = lo;
        }
    } else {
        // ---- cast h (f32) -> fb (bf16) ----
        int i = (bb - 385) * 256 + t;
        if (i < t4) {
            float4 v = ((const float4*)h)[i];
            ushort4 o;
            o.x = f2b(v.x); o.y = f2b(v.y); o.z = f2b(v.z); o.w = f2b(v.w);
            ((ushort4*)fb)[i] = o;
        }
    }
}

// ===================== dispatch 2: per-bucket CSR build =====================

__global__ __launch_bounds__(1024) void k_bucket(
    const uint* __restrict__ ebuf, const int* __restrict__ bcount,
    int* __restrict__ csrf, int* __restrict__ deg, float* __restrict__ invdeg,
    int N) {
    __shared__ int ldeg[256];
    __shared__ int lcsr[256 * SLOTS];
    int b = blockIdx.x, t = threadIdx.x;
    if (t < 256) ldeg[t] = 0;
    __syncthreads();
    int cnt = bcount[b];
    if (cnt > CAP) cnt = CAP;
    const uint* __restrict__ eb = ebuf + (size_t)b * CAP;
    for (int i = t; i < cnt; i += 1024) {
        uint r = eb[i];
        int dl = r & 255;
        int sl = atomicAdd(&ldeg[dl], 1);
        if (sl < SLOTS) lcsr[dl * SLOTS + sl] = (int)(r >> 8);
    }
    __syncthreads();
    int n0 = b << 8;
    int lim = (N - n0) * SLOTS;
    if (lim > 256 * SLOTS) lim = 256 * SLOTS;
    for (int i = t; i < lim; i += 1024)
        csrf[(size_t)n0 * SLOTS + i] = lcsr[i];
    if (t < 256 && n0 + t < N) {
        int d = ldeg[t];
        deg[n0 + t] = d;
        invdeg[n0 + t] = 1.0f / (float)(d > 1 ? d : 1);
    }
}

// ===================== dispatch 3: aggb | part2 =============================
// aggb (blocks [0,AB)): L3-latency-bound gather at high occupancy, tiny
// resource footprint -> huge idle issue capacity. part2 (blocks [AB,AB+256)):
// scatter/atomic workload hides in those idle slots. ebuf2 must NOT alias
// csrf here (aggb reads csrf concurrently) -> dedicated ws region (guarded).

__global__ __launch_bounds__(256) void k_agp(
    const ushort* __restrict__ fb, const int* __restrict__ deg,
    const int* __restrict__ csrf, const float* __restrict__ invdeg,
    ushort* __restrict__ outb, int N, int AB,
    const int* __restrict__ src, const int* __restrict__ dst,
    const int* __restrict__ gid,
    int* __restrict__ bcount2, uint* __restrict__ ebuf2, int E, int NB) {
    __shared__ int hist[512], base[512], lcur[512];

    if (blockIdx.x >= AB) {
        // ---------------- part2: src-bucket partition ----------------
        int bb = blockIdx.x - AB;   // 0..255
        int t = threadIdx.x;
        int per = (E + 255) / 256;
        int e0 = bb * per;
        int e1 = min(e0 + per, E);
        for (int i = t; i < NB; i += 256) { hist[i] = 0; lcur[i] = 0; }
        __syncthreads();
        for (int e = e0 + t; e < e1; e += 256) atomicAdd(&hist[src[e] >> 8], 1);
        __syncthreads();
        for (int i = t; i < NB; i += 256)
            base[i] = hist[i] ? atomicAdd(&bcount2[i], hist[i]) : 0;
        __syncthreads();
        for (int e = e0 + t; e < e1; e += 256) {
            int ss = src[e];
            int dd = dst[e];
            int bk = ss >> 8;
            int off = atomicAdd(&lcur[bk], 1);
            int pos = base[bk] + off;
            if (pos < CAP) {
                int g  = gid[dd];                 // 0..63
                int dc = deg[dd]; if (dc > 127) dc = 127;
                ebuf2[(size_t)bk * CAP + pos] =
                    (uint)(ss & 255) | ((uint)g << 8) | ((uint)dc << 14);
            }
        }
        return;
    }

    // ---------------- aggb: bf16 neighbor-mean gather ----------------
    int lane = threadIdx.x & 63;
    int n = blockIdx.x * 4 + (threadIdx.x >> 6);
    if (n >= N) return;
    int d = deg[n];
    if (d > SLOTS) d = SLOTS;
    const int* __restrict__ lst = csrf + (size_t)n * SLOTS;
    int ej = lane >> 4;      // 0..3
    int cg = lane & 15;      // cols cg*8 .. cg*8+7

    float acc[8];
#pragma unroll
    for (int i = 0; i < 8; i++) acc[i] = 0.f;

    int e = ej;
    for (; e + 4 < d; e += 8) {
        int s0 = lst[e];
        int s1 = lst[e + 4];
        uint4 v0 = *(const uint4*)(fb + (size_t)s0 * D + cg * 8);
        uint4 v1 = *(const uint4*)(fb + (size_t)s1 * D + cg * 8);
        acc[0] += __uint_as_float(v0.x << 16);
        acc[1] += __uint_as_float(v0.x & 0xffff0000u);
        acc[2] += __uint_as_float(v0.y << 16);
        acc[3] += __uint_as_float(v0.y & 0xffff0000u);
        acc[4] += __uint_as_float(v0.z << 16);
        acc[5] += __uint_as_float(v0.z & 0xffff0000u);
        acc[6] += __uint_as_float(v0.w << 16);
        acc[7] += __uint_as_float(v0.w & 0xffff0000u);
        acc[0] += __uint_as_float(v1.x << 16);
        acc[1] += __uint_as_float(v1.x & 0xffff0000u);
        acc[2] += __uint_as_float(v1.y << 16);
        acc[3] += __uint_as_float(v1.y & 0xffff0000u);
        acc[4] += __uint_as_float(v1.z << 16);
        acc[5] += __uint_as_float(v1.z & 0xffff0000u);
        acc[6] += __uint_as_float(v1.w << 16);
        acc[7] += __uint_as_float(v1.w & 0xffff0000u);
    }
    for (; e < d; e += 4) {
        int s = lst[e];
        uint4 v = *(const uint4*)(fb + (size_t)s * D + cg * 8);
        acc[0] += __uint_as_float(v.x << 16);
        acc[1] += __uint_as_float(v.x & 0xffff0000u);
        acc[2] += __uint_as_float(v.y << 16);
        acc[3] += __uint_as_float(v.y & 0xffff0000u);
        acc[4] += __uint_as_float(v.z << 16);
        acc[5] += __uint_as_float(v.z & 0xffff0000u);
        acc[6] += __uint_as_float(v.w << 16);
        acc[7] += __uint_as_float(v.w & 0xffff0000u);
    }
#pragma unroll
    for (int i = 0; i < 8; i++) {
        acc[i] += __shfl_xor(acc[i], 16);
        acc[i] += __shfl_xor(acc[i], 32);
    }
    if (ej == 0) {
        float id = invdeg[n];
        uint4 o;
        o.x = (uint)f2b(acc[0] * id) | ((uint)f2b(acc[1] * id) << 16);
        o.y = (uint)f2b(acc[2] * id) | ((uint)f2b(acc[3] * id) << 16);
        o.z = (uint)f2b(acc[4] * id) | ((uint)f2b(acc[5] * id) << 16);
        o.w = (uint)f2b(acc[6] * id) | ((uint)f2b(acc[7] * id) << 16);
        *(uint4*)(outb + (size_t)n * D + cg * 8) = o;
    }
}

// ---- fallback standalone part2 (only if workspace too small for ebuf2d) ----
__global__ __launch_bounds__(256) void k_part2s(
    const int* __restrict__ src, const int* __restrict__ dst,
    const int* __restrict__ gid, const int* __restrict__ deg,
    int* __restrict__ bcount2, uint* __restrict__ ebuf2, int E, int NB) {
    __shared__ int hist[512], base[512], lcur[512];
    int t = threadIdx.x;
    int per = (E + 255) / 256;
    int e0 = blockIdx.x * per;
    int e1 = min(e0 + per, E);
    for (int i = t; i < NB; i += 256) { hist[i] = 0; lcur[i] = 0; }
    __syncthreads();
    for (int e = e0 + t; e < e1; e += 256) atomicAdd(&hist[src[e] >> 8], 1);
    __syncthreads();
    for (int i = t; i < NB; i += 256)
        base[i] = hist[i] ? atomicAdd(&bcount2[i], hist[i]) : 0;
    __syncthreads();
    for (int e = e0 + t; e < e1; e += 256) {
        int ss = src[e];
        int dd = dst[e];
        int bk = ss >> 8;
        int off = atomicAdd(&lcur[bk], 1);
        int pos = base[bk] + off;
        if (pos < CAP) {
            int g  = gid[dd];
            int dc = deg[dd]; if (dc > 127) dc = 127;
            ebuf2[(size_t)bk * CAP + pos] =
                (uint)(ss & 255) | ((uint)g << 8) | ((uint)dc << 14);
        }
    }
}

// ===================== dispatch 4: mm1m (pure GEMM) =========================

__global__ __launch_bounds__(256, 2) void k_mm1m(
    const ushort* __restrict__ hb, const ushort* __restrict__ nbb,
    const ushort* __restrict__ wT, const float* __restrict__ b,
    ushort* __restrict__ x1b, int N) {
    __shared__ __align__(16) ushort As[128 * LDA];
    __shared__ __align__(16) ushort Bs[128 * LDA];
    int t    = threadIdx.x;
    int w    = t >> 6;
    int lane = t & 63;
    int m    = lane & 15;
    int quad = lane >> 4;
    int n0   = blockIdx.x * 128;

    f32x4 acc[2][8];
#pragma unroll
    for (int rt = 0; rt < 2; rt++)
#pragma unroll
        for (int ct = 0; ct < 8; ct++) acc[rt][ct] = (f32x4){0.f, 0.f, 0.f, 0.f};

#pragma unroll 1
    for (int kc = 0; kc < 8; kc++) {
        int k0 = kc * 32;
        const ushort* __restrict__ A = (k0 < 128) ? hb : nbb;
        int ka = k0 & 127;
        __syncthreads();
#pragma unroll
        for (int i = 0; i < 2; i++) {
            int linear = i * 256 + t;       // 0..511
            int row = linear >> 2;
            int q   = linear & 3;
            int nn = n0 + row;
            uint4 v = make_uint4(0u, 0u, 0u, 0u);
            if (nn < N) v = *(const uint4*)(A + (size_t)nn * D + ka + q * 8);
            *(uint4*)(&As[row * LDA + q * 8]) = v;
        }
#pragma unroll
        for (int i = 0; i < 2; i++) {
            int linear = i * 256 + t;
            int col = linear >> 2;
            int q   = linear & 3;
            uint4 v = *(const uint4*)(wT + (size_t)col * 256 + k0 + q * 8);
            *(uint4*)(&Bs[col * LDA + q * 8]) = v;
        }
        __syncthreads();
        short8 af[2], bf[8];
#pragma unroll
        for (int rt = 0; rt < 2; rt++)
            af[rt] = *(const short8*)(&As[(w * 32 + rt * 16 + m) * LDA + quad * 8]);
#pragma unroll
        for (int ct = 0; ct < 8; ct++)
            bf[ct] = *(const short8*)(&Bs[(ct * 16 + m) * LDA + quad * 8]);
#pragma unroll
        for (int rt = 0; rt < 2; rt++)
#pragma unroll
            for (int ct = 0; ct < 8; ct++)
                acc[rt][ct] = __builtin_amdgcn_mfma_f32_16x16x32_bf16(
                    af[rt], bf[ct], acc[rt][ct], 0, 0, 0);
    }
#pragma unroll
    for (int ct = 0; ct < 8; ct++) {
        float bias = b[ct * 16 + m];
#pragma unroll
        for (int rt = 0; rt < 2; rt++) {
#pragma unroll
            for (int r = 0; r < 4; r++) {
                int n = n0 + w * 32 + rt * 16 + quad * 4 + r;
                if (n < N)
                    x1b[(size_t)n * D + ct * 16 + m] =
                        f2b(fmaxf(acc[rt][ct][r] + bias, 0.f));
            }
        }
    }
}

// ===================== dispatch 5: ws2 | gsum1 ==============================

__global__ __launch_bounds__(1024, 4) void k_wg(
    const uint* __restrict__ ebuf2, const int* __restrict__ bcount2,
    const ushort* __restrict__ x1b, const int* __restrict__ gstart,
    float* __restrict__ S1, float* __restrict__ P, int N, int WSB) {
    __shared__ __align__(16) char smem[131072];   // 128 KiB

    if (blockIdx.x >= WSB) {
        // ---------------- gsum1 ----------------
        int b2 = blockIdx.x - WSB;    // 0..127
        int g  = b2 >> 1;
        int ch = b2 & 1;
        int r0 = gstart[g], r1 = gstart[g + 1];
        int len = r1 - r0;
        if (len <= 0) return;
        int L = (len + 1) >> 1;
        int a = r0 + ch * L;
        int bnd = min(a + L, r1);
        if (a >= bnd) return;
        int rp = threadIdx.x >> 6;    // 0..15 row phase
        int cp = threadIdx.x & 63;    // col pair
        float ax = 0.f, ay = 0.f;
        const uint* __restrict__ M = (const uint*)x1b;
        for (int n = a + rp; n < bnd; n += 16) {
            uint v = M[(size_t)n * 64 + cp];
            ax += __uint_as_float(v << 16);
            ay += __uint_as_float(v & 0xffff0000u);
        }
        atomicAdd(&S1[g * D + cp * 2], ax);
        atomicAdd(&S1[g * D + cp * 2 + 1], ay);
        return;
    }

    // ---------------- ws2 ----------------
    float*  lwcT = (float*)smem;             // [64][256] f32 (build phase)
    ushort* lxT  = (ushort*)smem;            // [128][256] u16 swz (overwrites lwcT)
    ushort* lwcb = (ushort*)(smem + 65536);  // [64][256] u16 swz (hi)
    ushort* lwlo = (ushort*)(smem + 98304);  // [64][256] u16 swz (lo)

    int b = blockIdx.x, t = threadIdx.x;
    int n0 = b << 8;

    for (int i = t; i < 16384; i += 1024) lwcT[i] = 0.f;
    __syncthreads();

    int cnt = bcount2[b];
    if (cnt > CAP) cnt = CAP;
    const uint* __restrict__ eb = ebuf2 + (size_t)b * CAP;
    for (int i = t; i < cnt; i += 1024) {
        uint r = eb[i];
        int sl = (int)(r & 255u);
        int g  = (int)((r >> 8) & 63u);
        int dc = (int)((r >> 14) & 127u);
        float id = 1.0f / (float)(dc > 1 ? dc : 1);   // == invdeg[dst] exactly
        atomicAdd(&lwcT[g * 256 + sl], id);           // bank = sl&31: random, ~2-way
    }
    __syncthreads();

    for (int i = t; i < 16384; i += 1024) {
        int g = i >> 8, sl = i & 255;
        float v = lwcT[i];
        ushort hi = f2b(v);
        float fhi = __uint_as_float((uint)hi << 16);
        ushort lo = f2b(v - fhi);
        int si = swz2i(g, sl);
        lwcb[si] = hi;
        lwlo[si] = lo;
    }
    __syncthreads();   // lwcT fully consumed -> safe to overwrite with lxT

    const uint4* __restrict__ x4 = (const uint4*)x1b;
#pragma unroll 1
    for (int it = 0; it < 4; ++it) {
        int l = it * 1024 + t;
        int n = l >> 4, q = l & 15;
        uint4 v = make_uint4(0u, 0u, 0u, 0u);
        int nn = n0 + n;
        if (nn < N) v = x4[(size_t)nn * 16 + q];
        int d0 = q * 8;
        lxT[swz2i(d0 + 0, n)] = (ushort)(v.x & 0xffffu);
        lxT[swz2i(d0 + 1, n)] = (ushort)(v.x >> 16);
        lxT[swz2i(d0 + 2, n)] = (ushort)(v.y & 0xffffu);
        lxT[swz2i(d0 + 3, n)] = (ushort)(v.y >> 16);
        lxT[swz2i(d0 + 4, n)] = (ushort)(v.z & 0xffffu);
        lxT[swz2i(d0 + 5, n)] = (ushort)(v.z >> 16);
        lxT[swz2i(d0 + 6, n)] = (ushort)(v.w & 0xffffu);
        lxT[swz2i(d0 + 7, n)] = (ushort)(v.w >> 16);
    }
    __syncthreads();

    int wv = t >> 6, lane = t & 63, m = lane & 15, quad = lane >> 4;
    int s  = wv & 3;     // g-strip (16 rows)
    int hs = wv >> 2;    // d-strip (32 cols)
    f32x4 acc[2];
    acc[0] = (f32x4){0.f, 0.f, 0.f, 0.f};
    acc[1] = (f32x4){0.f, 0.f, 0.f, 0.f};

#pragma unroll 1
    for (int k8 = 0; k8 < 8; ++k8) {
        int kc = k8 * 32 + quad * 8;
        int ar = s * 16 + m;
        short8 ahi = *(const short8*)&lwcb[swz2i(ar, kc)];
        short8 alo = *(const short8*)&lwlo[swz2i(ar, kc)];
#pragma unroll
        for (int d2 = 0; d2 < 2; ++d2) {
            short8 bfr = *(const short8*)&lxT[swz2i(hs * 32 + d2 * 16 + m, kc)];
            acc[d2] = __builtin_amdgcn_mfma_f32_16x16x32_bf16(alo, bfr, acc[d2], 0, 0, 0);
            acc[d2] = __builtin_amdgcn_mfma_f32_16x16x32_bf16(ahi, bfr, acc[d2], 0, 0, 0);
        }
    }
    float* __restrict__ Pb = P + (size_t)b * 8192;
#pragma unroll
    for (int d2 = 0; d2 < 2; ++d2) {
#pragma unroll
        for (int r = 0; r < 4; ++r) {
            int g = s * 16 + quad * 4 + r;
            Pb[g * 128 + hs * 32 + d2 * 16 + m] = acc[d2][r];
        }
    }
}

// ===================== dispatch 6: final (P-reduce + tiny matmuls) ==========

__global__ __launch_bounds__(256) void k_final(
    const float* __restrict__ S1, const float* __restrict__ P, int NBLK,
    const int* __restrict__ gstart, const float* __restrict__ W2s,
    const float* __restrict__ W2n, const float* __restrict__ b2,
    const float* __restrict__ Wc, const float* __restrict__ bc,
    float* __restrict__ out) {
    __shared__ float s1[D], s2[2][D], hg[D];
    int g = blockIdx.x, t = threadIdx.x;
    int c = t & 127, hh = t >> 7;
    const float* __restrict__ Pg = P + (size_t)g * 128 + c;
    float a0 = 0.f, a1 = 0.f, a2 = 0.f, a3 = 0.f;
    int bb = hh;
    for (; bb + 6 < NBLK; bb += 8) {
        a0 += Pg[(size_t)bb * 8192];
        a1 += Pg[(size_t)(bb + 2) * 8192];
        a2 += Pg[(size_t)(bb + 4) * 8192];
        a3 += Pg[(size_t)(bb + 6) * 8192];
    }
    for (; bb < NBLK; bb += 2) a0 += Pg[(size_t)bb * 8192];
    s2[hh][c] = a0 + a1 + a2 + a3;
    if (hh == 0) s1[c] = S1[g * D + c];
    __syncthreads();
    if (t < 128) s2[0][c] += s2[1][c];
    __syncthreads();
    if (t < 128) {
        float acc = 0.f;
#pragma unroll 8
        for (int k = 0; k < D; k++) {
            acc = fmaf(s1[k], W2s[k * D + c], acc);
            acc = fmaf(s2[0][k], W2n[k * D + c], acc);
        }
        int cnt = gstart[g + 1] - gstart[g];
        hg[c] = (cnt > 0) ? (acc / (float)cnt + b2[c]) : 0.f;
    }
    __syncthreads();
    if (t < N_CLS) {
        float o = bc[t];
        for (int k = 0; k < D; k++) o = fmaf(hg[k], Wc[k * N_CLS + t], o);
        out[g * N_CLS + t] = o;
    }
}

// ===================== launch ===============================================

extern "C" void kernel_launch(void* const* d_in, const int* in_sizes, int n_in,
                              void* d_out, int out_size, void* d_ws, size_t ws_size,
                              hipStream_t stream) {
    const float* h   = (const float*)d_in[0];
    const int*   src = (const int*)d_in[1];
    const int*   dst = (const int*)d_in[2];
    const int*   gid = (const int*)d_in[3];
    const float* W1s = (const float*)d_in[5];
    const float* W1n = (const float*)d_in[6];
    const float* b1  = (const float*)d_in[7];
    const float* W2s = (const float*)d_in[8];
    const float* W2n = (const float*)d_in[9];
    const float* b2  = (const float*)d_in[10];
    const float* Wc  = (const float*)d_in[11];
    const float* bc  = (const float*)d_in[12];
    float* out = (float*)d_out;

    const int N = in_sizes[0] / D;  // 100000
    const int E = in_sizes[1];      // 1600000
    const int NB = (N + 255) >> 8;  // 391 buckets

    char* w = (char*)d_ws;
    size_t off = 0;
    auto alloc = [&](size_t elems) -> void* {   // elems are 4-byte units
        void* p = w + off;
        off += elems * 4;
        return p;
    };
    // zero-initialized region first (one memset)
    float* S1      = (float*)alloc((size_t)N_GRAPHS * D);
    int*   bcount  = (int*)alloc(512);
    int*   bcount2 = (int*)alloc(512);
    size_t zero_bytes = off;
    int*   deg    = (int*)alloc(N);
    float* invdeg = (float*)alloc(N);
    int*   gstart = (int*)alloc(128);
    int*   csrf   = (int*)alloc((size_t)N * SLOTS);   // 19.2 MB padded CSR
    ushort* fb    = (ushort*)alloc((size_t)N * 64);   // bf16 [N,128] h
    ushort* nbb   = (ushort*)alloc((size_t)N * 64);   // bf16 [N,128] neigh1
    ushort* x1b   = (ushort*)alloc((size_t)N * 64);   // bf16 [N,128] x1
    ushort* wT    = (ushort*)alloc(16384);            // bf16 [128 cols][256 k]
    // aliases (dead-buffer reuse):
    uint*  ebuf = (uint*)nbb;    // dst-buckets: dead once k_agp writes nbb
    float* P    = (float*)fb;    // [NB][64*128] partials: fb dead after k_mm1m

    // ebuf2: prefer a DEDICATED region (lets part2 ride inside the aggb
    // dispatch -- it cannot alias csrf there, since aggb reads csrf
    // concurrently). Fall back to csrf-alias + standalone part2 if ws small.
    size_t ebuf2_units = (size_t)NB * CAP;
    bool dedicated = (off + ebuf2_units * 4) <= ws_size;
    uint* ebuf2 = dedicated ? (uint*)alloc(ebuf2_units) : (uint*)csrf;

    hipMemsetAsync(d_ws, 0, zero_bytes, stream);

    int t4 = N * 32;                   // float4 count of [N,128] f32
    int CB = (t4 + 255) / 256;         // cast blocks
    int MMB = (N + 127) / 128;         // mm1m blocks
    int AB  = (N + 3) / 4;             // aggb blocks

    // 1: part | castw | gbound | cast
    k_boot<<<256 + 128 + 1 + CB, 256, 0, stream>>>(
        h, fb, W1s, W1n, wT, gid, gstart, src, dst, bcount, ebuf, E, NB, N, t4);
    // 2: CSR build
    k_bucket<<<NB, 1024, 0, stream>>>(ebuf, bcount, csrf, deg, invdeg, N);
    // 3: aggb | part2 (part2 hides in aggb's idle latency slots)
    k_agp<<<AB + (dedicated ? 256 : 0), 256, 0, stream>>>(
        fb, deg, csrf, invdeg, nbb, N, AB,
        src, dst, gid, bcount2, ebuf2, E, NB);
    // 3b (fallback only): standalone part2 into dead csrf
    if (!dedicated)
        k_part2s<<<256, 256, 0, stream>>>(src, dst, gid, deg, bcount2, ebuf2, E, NB);
    // 4: mm1m (pure GEMM)
    k_mm1m<<<MMB, 256, 0, stream>>>(fb, nbb, wT, b1, x1b, N);
    // 5: ws2 (MFMA collapse of layer-2 agg, partials to P) | gsum1
    k_wg<<<NB + 128, 1024, 0, stream>>>(
        ebuf2, bcount2, x1b, gstart, S1, P, N, NB);
    // 6: final (P reduction + output head)
    k_final<<<N_GRAPHS, 256, 0, stream>>>(
        S1, P, NB, gstart, W2s, W2n, b2, Wc, bc, out);
}

// Round 7
// 308.769 us; speedup vs baseline: 1.1456x; 1.1456x over previous
//
#include <hip/hip_runtime.h>

#define D        128
#define N_GRAPHS 64
#define N_CLS    16
#define LDA      40   // mm1m LDS row stride in bf16 (80 B: 16B-aligned, 2-way banks = free)
#define SLOTS    48   // padded CSR width; deg ~ Poisson(16), P(>48) ~ 1e-11
#define CAP      8192 // bucket capacity (avg 4096, std ~64 -> 2x margin)

typedef unsigned int   uint;
typedef unsigned short ushort;
typedef __attribute__((ext_vector_type(8))) short short8;
typedef __attribute__((ext_vector_type(4))) float f32x4;

__device__ inline ushort f2b(float f) {   // f32 -> bf16 RNE
    uint u = __float_as_uint(f);
    u += 0x7fffu + ((u >> 16) & 1u);
    return (ushort)(u >> 16);
}

// swizzled u16 index into a [row][256] LDS tile.
// XOR by ((row ^ (row>>3)) & 7) << 3: keeps 8-u16 (16 B) groups intact for
// b128 reads; varies with BOTH row&7 (spreads MFMA-read lanes) and row>>3
// (spreads transpose-staging writes). Both patterns <=2-way.
__device__ __forceinline__ int swz2i(int row, int col) {
    return row * 256 + (col ^ (((row ^ (row >> 3)) & 7) << 3));
}

// ========== dispatch 1: boot (part-dst | part-src | castw | gbound | cast) ==
// Both edge partitions in ONE dispatch: they stream the same src/dst arrays
// (L2 reuse), and neither competes with the gather phase's L2 working set.
// Records: dst-buckets (src<<8)|dst_lane ; src-buckets (dst<<8)|src_lane.

__global__ __launch_bounds__(256) void k_boot(
    const float* __restrict__ h, ushort* __restrict__ fb,
    const float* __restrict__ Ws, const float* __restrict__ Wn,
    ushort* __restrict__ wT,
    const int* __restrict__ gid, int* __restrict__ gstart,
    const int* __restrict__ src, const int* __restrict__ dst,
    int* __restrict__ bcount, uint* __restrict__ ebuf,
    int* __restrict__ bcount2, uint* __restrict__ ebuf2, int doP2,
    int E, int NB, int N, int t4) {
    __shared__ int hist[512], base[512], lcur[512];
    int bb = blockIdx.x;
    int t  = threadIdx.x;

    if (bb < 256) {
        // ---- partition edges into 256-node buckets by dst ----
        int per = (E + 255) / 256;
        int e0 = bb * per;
        int e1 = min(e0 + per, E);
        for (int i = t; i < NB; i += 256) { hist[i] = 0; lcur[i] = 0; }
        __syncthreads();
        for (int e = e0 + t; e < e1; e += 256) atomicAdd(&hist[dst[e] >> 8], 1);
        __syncthreads();
        for (int i = t; i < NB; i += 256)
            base[i] = hist[i] ? atomicAdd(&bcount[i], hist[i]) : 0;
        __syncthreads();
        for (int e = e0 + t; e < e1; e += 256) {
            int dd = dst[e];
            int b = dd >> 8;
            int off = atomicAdd(&lcur[b], 1);
            int pos = base[b] + off;
            if (pos < CAP)
                ebuf[(size_t)b * CAP + pos] = ((uint)src[e] << 8) | (uint)(dd & 255);
        }
    } else if (bb < 512) {
        // ---- partition edges into 256-node buckets by src ----
        if (!doP2) return;
        int bb2 = bb - 256;
        int per = (E + 255) / 256;
        int e0 = bb2 * per;
        int e1 = min(e0 + per, E);
        for (int i = t; i < NB; i += 256) { hist[i] = 0; lcur[i] = 0; }
        __syncthreads();
        for (int e = e0 + t; e < e1; e += 256) atomicAdd(&hist[src[e] >> 8], 1);
        __syncthreads();
        for (int i = t; i < NB; i += 256)
            base[i] = hist[i] ? atomicAdd(&bcount2[i], hist[i]) : 0;
        __syncthreads();
        for (int e = e0 + t; e < e1; e += 256) {
            int ss = src[e];
            int bk = ss >> 8;
            int off = atomicAdd(&lcur[bk], 1);
            int pos = base[bk] + off;
            if (pos < CAP)
                ebuf2[(size_t)bk * CAP + pos] =
                    ((uint)dst[e] << 8) | (uint)(ss & 255);
        }
    } else if (bb < 640) {
        // ---- castw: wT[col][k] (k=0..255: Ws rows then Wn rows), bf16 ----
        int i = (bb - 512) * 256 + t;   // 0..32767
        int c = i >> 8, k = i & 255;
        float v = (k < 128) ? Ws[k * 128 + c] : Wn[(k - 128) * 128 + c];
        wT[c * 256 + k] = f2b(v);
    } else if (bb == 640) {
        // ---- gbound: gstart[g] = lower_bound(gid, g) ----
        int g = t;
        if (g <= N_GRAPHS) {
            int lo = 0, hi = N;
            while (lo < hi) {
                int mid = (lo + hi) >> 1;
                if (gid[mid] < g) lo = mid + 1; else hi = mid;
            }
            gstart[g] = lo;
        }
    } else {
        // ---- cast h (f32) -> fb (bf16) ----
        int i = (bb - 641) * 256 + t;
        if (i < t4) {
            float4 v = ((const float4*)h)[i];
            ushort4 o;
            o.x = f2b(v.x); o.y = f2b(v.y); o.z = f2b(v.z); o.w = f2b(v.w);
            ((ushort4*)fb)[i] = o;
        }
    }
}

// ===================== dispatch 2: per-bucket CSR build =====================
// Epilogue also emits gipack[n] = {gid[n], invdeg[n]} (one 8B L2-resident
// lookup per edge in k_wg instead of two 4B ones).

__global__ __launch_bounds__(1024) void k_bucket(
    const uint* __restrict__ ebuf, const int* __restrict__ bcount,
    const int* __restrict__ gid,
    int* __restrict__ csrf, int* __restrict__ deg, float* __restrict__ invdeg,
    uint2* __restrict__ gipack, int N) {
    __shared__ int ldeg[256];
    __shared__ int lcsr[256 * SLOTS];
    int b = blockIdx.x, t = threadIdx.x;
    if (t < 256) ldeg[t] = 0;
    __syncthreads();
    int cnt = bcount[b];
    if (cnt > CAP) cnt = CAP;
    const uint* __restrict__ eb = ebuf + (size_t)b * CAP;
    for (int i = t; i < cnt; i += 1024) {
        uint r = eb[i];
        int dl = r & 255;
        int sl = atomicAdd(&ldeg[dl], 1);
        if (sl < SLOTS) lcsr[dl * SLOTS + sl] = (int)(r >> 8);
    }
    __syncthreads();
    int n0 = b << 8;
    int lim = (N - n0) * SLOTS;
    if (lim > 256 * SLOTS) lim = 256 * SLOTS;
    for (int i = t; i < lim; i += 1024)
        csrf[(size_t)n0 * SLOTS + i] = lcsr[i];
    if (t < 256 && n0 + t < N) {
        int d = ldeg[t];
        deg[n0 + t] = d;
        float iv = 1.0f / (float)(d > 1 ? d : 1);
        invdeg[n0 + t] = iv;
        gipack[n0 + t] = make_uint2((uint)gid[n0 + t], __float_as_uint(iv));
    }
}

// ===================== dispatch 3: bf16 neighbor-mean gather (pure) =========

__global__ __launch_bounds__(256) void k_aggb(
    const ushort* __restrict__ fb, const int* __restrict__ deg,
    const int* __restrict__ csrf, const float* __restrict__ invdeg,
    ushort* __restrict__ outb, int N) {
    int lane = threadIdx.x & 63;
    int n = blockIdx.x * 4 + (threadIdx.x >> 6);
    if (n >= N) return;
    int d = deg[n];
    if (d > SLOTS) d = SLOTS;
    const int* __restrict__ lst = csrf + (size_t)n * SLOTS;
    int ej = lane >> 4;      // 0..3
    int cg = lane & 15;      // cols cg*8 .. cg*8+7

    float acc[8];
#pragma unroll
    for (int i = 0; i < 8; i++) acc[i] = 0.f;

    int e = ej;
    for (; e + 4 < d; e += 8) {
        int s0 = lst[e];
        int s1 = lst[e + 4];
        uint4 v0 = *(const uint4*)(fb + (size_t)s0 * D + cg * 8);
        uint4 v1 = *(const uint4*)(fb + (size_t)s1 * D + cg * 8);
        acc[0] += __uint_as_float(v0.x << 16);
        acc[1] += __uint_as_float(v0.x & 0xffff0000u);
        acc[2] += __uint_as_float(v0.y << 16);
        acc[3] += __uint_as_float(v0.y & 0xffff0000u);
        acc[4] += __uint_as_float(v0.z << 16);
        acc[5] += __uint_as_float(v0.z & 0xffff0000u);
        acc[6] += __uint_as_float(v0.w << 16);
        acc[7] += __uint_as_float(v0.w & 0xffff0000u);
        acc[0] += __uint_as_float(v1.x << 16);
        acc[1] += __uint_as_float(v1.x & 0xffff0000u);
        acc[2] += __uint_as_float(v1.y << 16);
        acc[3] += __uint_as_float(v1.y & 0xffff0000u);
        acc[4] += __uint_as_float(v1.z << 16);
        acc[5] += __uint_as_float(v1.z & 0xffff0000u);
        acc[6] += __uint_as_float(v1.w << 16);
        acc[7] += __uint_as_float(v1.w & 0xffff0000u);
    }
    for (; e < d; e += 4) {
        int s = lst[e];
        uint4 v = *(const uint4*)(fb + (size_t)s * D + cg * 8);
        acc[0] += __uint_as_float(v.x << 16);
        acc[1] += __uint_as_float(v.x & 0xffff0000u);
        acc[2] += __uint_as_float(v.y << 16);
        acc[3] += __uint_as_float(v.y & 0xffff0000u);
        acc[4] += __uint_as_float(v.z << 16);
        acc[5] += __uint_as_float(v.z & 0xffff0000u);
        acc[6] += __uint_as_float(v.w << 16);
        acc[7] += __uint_as_float(v.w & 0xffff0000u);
    }
#pragma unroll
    for (int i = 0; i < 8; i++) {
        acc[i] += __shfl_xor(acc[i], 16);
        acc[i] += __shfl_xor(acc[i], 32);
    }
    if (ej == 0) {
        float id = invdeg[n];
        uint4 o;
        o.x = (uint)f2b(acc[0] * id) | ((uint)f2b(acc[1] * id) << 16);
        o.y = (uint)f2b(acc[2] * id) | ((uint)f2b(acc[3] * id) << 16);
        o.z = (uint)f2b(acc[4] * id) | ((uint)f2b(acc[5] * id) << 16);
        o.w = (uint)f2b(acc[6] * id) | ((uint)f2b(acc[7] * id) << 16);
        *(uint4*)(outb + (size_t)n * D + cg * 8) = o;
    }
}

// ---- fallback standalone part2 (only if ws too small for dedicated ebuf2):
// runs after aggb, writing into dead csrf space. Record: (dst<<8)|src_lane.
__global__ __launch_bounds__(256) void k_part2s(
    const int* __restrict__ src, const int* __restrict__ dst,
    int* __restrict__ bcount2, uint* __restrict__ ebuf2, int E, int NB) {
    __shared__ int hist[512], base[512], lcur[512];
    int t = threadIdx.x;
    int per = (E + 255) / 256;
    int e0 = blockIdx.x * per;
    int e1 = min(e0 + per, E);
    for (int i = t; i < NB; i += 256) { hist[i] = 0; lcur[i] = 0; }
    __syncthreads();
    for (int e = e0 + t; e < e1; e += 256) atomicAdd(&hist[src[e] >> 8], 1);
    __syncthreads();
    for (int i = t; i < NB; i += 256)
        base[i] = hist[i] ? atomicAdd(&bcount2[i], hist[i]) : 0;
    __syncthreads();
    for (int e = e0 + t; e < e1; e += 256) {
        int ss = src[e];
        int bk = ss >> 8;
        int off = atomicAdd(&lcur[bk], 1);
        int pos = base[bk] + off;
        if (pos < CAP)
            ebuf2[(size_t)bk * CAP + pos] = ((uint)dst[e] << 8) | (uint)(ss & 255);
    }
}

// ===================== dispatch 4: mm1m (pure GEMM) =========================

__global__ __launch_bounds__(256, 2) void k_mm1m(
    const ushort* __restrict__ hb, const ushort* __restrict__ nbb,
    const ushort* __restrict__ wT, const float* __restrict__ b,
    ushort* __restrict__ x1b, int N) {
    __shared__ __align__(16) ushort As[128 * LDA];
    __shared__ __align__(16) ushort Bs[128 * LDA];
    int t    = threadIdx.x;
    int w    = t >> 6;
    int lane = t & 63;
    int m    = lane & 15;
    int quad = lane >> 4;
    int n0   = blockIdx.x * 128;

    f32x4 acc[2][8];
#pragma unroll
    for (int rt = 0; rt < 2; rt++)
#pragma unroll
        for (int ct = 0; ct < 8; ct++) acc[rt][ct] = (f32x4){0.f, 0.f, 0.f, 0.f};

#pragma unroll 1
    for (int kc = 0; kc < 8; kc++) {
        int k0 = kc * 32;
        const ushort* __restrict__ A = (k0 < 128) ? hb : nbb;
        int ka = k0 & 127;
        __syncthreads();
#pragma unroll
        for (int i = 0; i < 2; i++) {
            int linear = i * 256 + t;       // 0..511
            int row = linear >> 2;
            int q   = linear & 3;
            int nn = n0 + row;
            uint4 v = make_uint4(0u, 0u, 0u, 0u);
            if (nn < N) v = *(const uint4*)(A + (size_t)nn * D + ka + q * 8);
            *(uint4*)(&As[row * LDA + q * 8]) = v;
        }
#pragma unroll
        for (int i = 0; i < 2; i++) {
            int linear = i * 256 + t;
            int col = linear >> 2;
            int q   = linear & 3;
            uint4 v = *(const uint4*)(wT + (size_t)col * 256 + k0 + q * 8);
            *(uint4*)(&Bs[col * LDA + q * 8]) = v;
        }
        __syncthreads();
        short8 af[2], bf[8];
#pragma unroll
        for (int rt = 0; rt < 2; rt++)
            af[rt] = *(const short8*)(&As[(w * 32 + rt * 16 + m) * LDA + quad * 8]);
#pragma unroll
        for (int ct = 0; ct < 8; ct++)
            bf[ct] = *(const short8*)(&Bs[(ct * 16 + m) * LDA + quad * 8]);
#pragma unroll
        for (int rt = 0; rt < 2; rt++)
#pragma unroll
            for (int ct = 0; ct < 8; ct++)
                acc[rt][ct] = __builtin_amdgcn_mfma_f32_16x16x32_bf16(
                    af[rt], bf[ct], acc[rt][ct], 0, 0, 0);
    }
#pragma unroll
    for (int ct = 0; ct < 8; ct++) {
        float bias = b[ct * 16 + m];
#pragma unroll
        for (int rt = 0; rt < 2; rt++) {
#pragma unroll
            for (int r = 0; r < 4; r++) {
                int n = n0 + w * 32 + rt * 16 + quad * 4 + r;
                if (n < N)
                    x1b[(size_t)n * D + ct * 16 + m] =
                        f2b(fmaxf(acc[rt][ct][r] + bias, 0.f));
            }
        }
    }
}

// ===================== dispatch 5: ws2 | gsum1 ==============================

__global__ __launch_bounds__(1024, 4) void k_wg(
    const uint* __restrict__ ebuf2, const int* __restrict__ bcount2,
    const uint2* __restrict__ gipack,
    const ushort* __restrict__ x1b, const int* __restrict__ gstart,
    float* __restrict__ S1, float* __restrict__ P, int N, int WSB) {
    __shared__ __align__(16) char smem[131072];   // 128 KiB

    if (blockIdx.x >= WSB) {
        // ---------------- gsum1 ----------------
        int b2 = blockIdx.x - WSB;    // 0..127
        int g  = b2 >> 1;
        int ch = b2 & 1;
        int r0 = gstart[g], r1 = gstart[g + 1];
        int len = r1 - r0;
        if (len <= 0) return;
        int L = (len + 1) >> 1;
        int a = r0 + ch * L;
        int bnd = min(a + L, r1);
        if (a >= bnd) return;
        int rp = threadIdx.x >> 6;    // 0..15 row phase
        int cp = threadIdx.x & 63;    // col pair
        float ax = 0.f, ay = 0.f;
        const uint* __restrict__ M = (const uint*)x1b;
        for (int n = a + rp; n < bnd; n += 16) {
            uint v = M[(size_t)n * 64 + cp];
            ax += __uint_as_float(v << 16);
            ay += __uint_as_float(v & 0xffff0000u);
        }
        atomicAdd(&S1[g * D + cp * 2], ax);
        atomicAdd(&S1[g * D + cp * 2 + 1], ay);
        return;
    }

    // ---------------- ws2 ----------------
    float*  lwcT = (float*)smem;             // [64][256] f32 (build phase)
    ushort* lxT  = (ushort*)smem;            // [128][256] u16 swz (overwrites lwcT)
    ushort* lwcb = (ushort*)(smem + 65536);  // [64][256] u16 swz (hi)
    ushort* lwlo = (ushort*)(smem + 98304);  // [64][256] u16 swz (lo)

    int b = blockIdx.x, t = threadIdx.x;
    int n0 = b << 8;

    for (int i = t; i < 16384; i += 1024) lwcT[i] = 0.f;
    __syncthreads();

    int cnt = bcount2[b];
    if (cnt > CAP) cnt = CAP;
    const uint* __restrict__ eb = ebuf2 + (size_t)b * CAP;
    for (int i = t; i < cnt; i += 1024) {
        uint r = eb[i];
        int dn = (int)(r >> 8);          // dst node
        int sl = (int)(r & 255u);        // src lane in bucket
        uint2 gi = gipack[dn];           // {gid[dn], bits(invdeg[dn])} 8B L2 hit
        atomicAdd(&lwcT[gi.x * 256 + sl], __uint_as_float(gi.y));
    }
    __syncthreads();

    for (int i = t; i < 16384; i += 1024) {
        int g = i >> 8, sl = i & 255;
        float v = lwcT[i];
        ushort hi = f2b(v);
        float fhi = __uint_as_float((uint)hi << 16);
        ushort lo = f2b(v - fhi);
        int si = swz2i(g, sl);
        lwcb[si] = hi;
        lwlo[si] = lo;
    }
    __syncthreads();   // lwcT fully consumed -> safe to overwrite with lxT

    const uint4* __restrict__ x4 = (const uint4*)x1b;
#pragma unroll 1
    for (int it = 0; it < 4; ++it) {
        int l = it * 1024 + t;
        int n = l >> 4, q = l & 15;
        uint4 v = make_uint4(0u, 0u, 0u, 0u);
        int nn = n0 + n;
        if (nn < N) v = x4[(size_t)nn * 16 + q];
        int d0 = q * 8;
        lxT[swz2i(d0 + 0, n)] = (ushort)(v.x & 0xffffu);
        lxT[swz2i(d0 + 1, n)] = (ushort)(v.x >> 16);
        lxT[swz2i(d0 + 2, n)] = (ushort)(v.y & 0xffffu);
        lxT[swz2i(d0 + 3, n)] = (ushort)(v.y >> 16);
        lxT[swz2i(d0 + 4, n)] = (ushort)(v.z & 0xffffu);
        lxT[swz2i(d0 + 5, n)] = (ushort)(v.z >> 16);
        lxT[swz2i(d0 + 6, n)] = (ushort)(v.w & 0xffffu);
        lxT[swz2i(d0 + 7, n)] = (ushort)(v.w >> 16);
    }
    __syncthreads();

    int wv = t >> 6, lane = t & 63, m = lane & 15, quad = lane >> 4;
    int s  = wv & 3;     // g-strip (16 rows)
    int hs = wv >> 2;    // d-strip (32 cols)
    f32x4 acc[2];
    acc[0] = (f32x4){0.f, 0.f, 0.f, 0.f};
    acc[1] = (f32x4){0.f, 0.f, 0.f, 0.f};

#pragma unroll 1
    for (int k8 = 0; k8 < 8; ++k8) {
        int kc = k8 * 32 + quad * 8;
        int ar = s * 16 + m;
        short8 ahi = *(const short8*)&lwcb[swz2i(ar, kc)];
        short8 alo = *(const short8*)&lwlo[swz2i(ar, kc)];
#pragma unroll
        for (int d2 = 0; d2 < 2; ++d2) {
            short8 bfr = *(const short8*)&lxT[swz2i(hs * 32 + d2 * 16 + m, kc)];
            acc[d2] = __builtin_amdgcn_mfma_f32_16x16x32_bf16(alo, bfr, acc[d2], 0, 0, 0);
            acc[d2] = __builtin_amdgcn_mfma_f32_16x16x32_bf16(ahi, bfr, acc[d2], 0, 0, 0);
        }
    }
    float* __restrict__ Pb = P + (size_t)b * 8192;
#pragma unroll
    for (int d2 = 0; d2 < 2; ++d2) {
#pragma unroll
        for (int r = 0; r < 4; ++r) {
            int g = s * 16 + quad * 4 + r;
            Pb[g * 128 + hs * 32 + d2 * 16 + m] = acc[d2][r];
        }
    }
}

// ===================== dispatch 6: final (P-reduce + tiny matmuls) ==========

__global__ __launch_bounds__(256) void k_final(
    const float* __restrict__ S1, const float* __restrict__ P, int NBLK,
    const int* __restrict__ gstart, const float* __restrict__ W2s,
    const float* __restrict__ W2n, const float* __restrict__ b2,
    const float* __restrict__ Wc, const float* __restrict__ bc,
    float* __restrict__ out) {
    __shared__ float s1[D], s2[2][D], hg[D];
    int g = blockIdx.x, t = threadIdx.x;
    int c = t & 127, hh = t >> 7;
    const float* __restrict__ Pg = P + (size_t)g * 128 + c;
    float a0 = 0.f, a1 = 0.f, a2 = 0.f, a3 = 0.f;
    int bb = hh;
    for (; bb + 6 < NBLK; bb += 8) {
        a0 += Pg[(size_t)bb * 8192];
        a1 += Pg[(size_t)(bb + 2) * 8192];
        a2 += Pg[(size_t)(bb + 4) * 8192];
        a3 += Pg[(size_t)(bb + 6) * 8192];
    }
    for (; bb < NBLK; bb += 2) a0 += Pg[(size_t)bb * 8192];
    s2[hh][c] = a0 + a1 + a2 + a3;
    if (hh == 0) s1[c] = S1[g * D + c];
    __syncthreads();
    if (t < 128) s2[0][c] += s2[1][c];
    __syncthreads();
    if (t < 128) {
        float acc = 0.f;
#pragma unroll 8
        for (int k = 0; k < D; k++) {
            acc = fmaf(s1[k], W2s[k * D + c], acc);
            acc = fmaf(s2[0][k], W2n[k * D + c], acc);
        }
        int cnt = gstart[g + 1] - gstart[g];
        hg[c] = (cnt > 0) ? (acc / (float)cnt + b2[c]) : 0.f;
    }
    __syncthreads();
    if (t < N_CLS) {
        float o = bc[t];
        for (int k = 0; k < D; k++) o = fmaf(hg[k], Wc[k * N_CLS + t], o);
        out[g * N_CLS + t] = o;
    }
}

// ===================== launch ===============================================

extern "C" void kernel_launch(void* const* d_in, const int* in_sizes, int n_in,
                              void* d_out, int out_size, void* d_ws, size_t ws_size,
                              hipStream_t stream) {
    const float* h   = (const float*)d_in[0];
    const int*   src = (const int*)d_in[1];
    const int*   dst = (const int*)d_in[2];
    const int*   gid = (const int*)d_in[3];
    const float* W1s = (const float*)d_in[5];
    const float* W1n = (const float*)d_in[6];
    const float* b1  = (const float*)d_in[7];
    const float* W2s = (const float*)d_in[8];
    const float* W2n = (const float*)d_in[9];
    const float* b2  = (const float*)d_in[10];
    const float* Wc  = (const float*)d_in[11];
    const float* bc  = (const float*)d_in[12];
    float* out = (float*)d_out;

    const int N = in_sizes[0] / D;  // 100000
    const int E = in_sizes[1];      // 1600000
    const int NB = (N + 255) >> 8;  // 391 buckets

    char* w = (char*)d_ws;
    size_t off = 0;
    auto alloc = [&](size_t elems) -> void* {   // elems are 4-byte units
        void* p = w + off;
        off += elems * 4;
        return p;
    };
    // zero-initialized region first (one memset)
    float* S1      = (float*)alloc((size_t)N_GRAPHS * D);
    int*   bcount  = (int*)alloc(512);
    int*   bcount2 = (int*)alloc(512);
    size_t zero_bytes = off;
    int*   deg    = (int*)alloc(N);
    float* invdeg = (float*)alloc(N);
    uint2* gipack = (uint2*)alloc((size_t)N * 2);     // {gid, invdeg} 800 KB
    int*   gstart = (int*)alloc(128);
    int*   csrf   = (int*)alloc((size_t)N * SLOTS);   // 19.2 MB padded CSR
    ushort* fb    = (ushort*)alloc((size_t)N * 64);   // bf16 [N,128] h
    ushort* nbb   = (ushort*)alloc((size_t)N * 64);   // bf16 [N,128] neigh1
    ushort* x1b   = (ushort*)alloc((size_t)N * 64);   // bf16 [N,128] x1
    ushort* wT    = (ushort*)alloc(16384);            // bf16 [128 cols][256 k]
    // aliases (dead-buffer reuse):
    uint*  ebuf = (uint*)nbb;    // dst-buckets: dead once k_aggb writes nbb
    float* P    = (float*)fb;    // [NB][64*128] partials: fb dead after k_mm1m

    // ebuf2: dedicated region preferred (lets part2 ride in k_boot; it must
    // stay live dispatch 1 -> 5 so no alias fits). Fallback: alias csrf and
    // run standalone part2 AFTER aggb (csrf dead then).
    size_t ebuf2_units = (size_t)NB * CAP;
    bool dedicated = (off + ebuf2_units * 4) <= ws_size;
    uint* ebuf2 = dedicated ? (uint*)alloc(ebuf2_units) : (uint*)csrf;

    hipMemsetAsync(d_ws, 0, zero_bytes, stream);

    int t4 = N * 32;                   // float4 count of [N,128] f32
    int CB = (t4 + 255) / 256;         // cast blocks
    int MMB = (N + 127) / 128;         // mm1m blocks
    int AB  = (N + 3) / 4;             // aggb blocks

    // 1: part-dst | part-src | castw | gbound | cast
    k_boot<<<641 + CB, 256, 0, stream>>>(
        h, fb, W1s, W1n, wT, gid, gstart, src, dst,
        bcount, ebuf, bcount2, ebuf2, dedicated ? 1 : 0, E, NB, N, t4);
    // 2: CSR build (+ gipack)
    k_bucket<<<NB, 1024, 0, stream>>>(ebuf, bcount, gid, csrf, deg, invdeg, gipack, N);
    // 3: neighbor-mean gather (pure)
    k_aggb<<<AB, 256, 0, stream>>>(fb, deg, csrf, invdeg, nbb, N);
    // 3b (fallback only): standalone part2 into dead csrf
    if (!dedicated)
        k_part2s<<<256, 256, 0, stream>>>(src, dst, bcount2, ebuf2, E, NB);
    // 4: mm1m (pure GEMM)
    k_mm1m<<<MMB, 256, 0, stream>>>(fb, nbb, wT, b1, x1b, N);
    // 5: ws2 (MFMA collapse of layer-2 agg, partials to P) | gsum1
    k_wg<<<NB + 128, 1024, 0, stream>>>(
        ebuf2, bcount2, gipack, x1b, gstart, S1, P, N, NB);
    // 6: final (P reduction + output head)
    k_final<<<N_GRAPHS, 256, 0, stream>>>(
        S1, P, NB, gstart, W2s, W2n, b2, Wc, bc, out);
}